// Round 19
// baseline (2111.574 us; speedup 1.0000x reference)
//
#include <hip/hip_runtime.h>
#include <cstdint>
#include <cmath>

#define T_SEQ 1024
#define BATCH 16
#define HID 96
#define G4 384
#define QKV_LD 288
#define HDIM 24
#define KKEEP 512
#define SCALE 0.20412414523193154f  // 1/sqrt(24)
#define L2E 1.4426950408889634f     // log2(e)

typedef _Float16 half2v __attribute__((ext_vector_type(2)));
typedef __bf16 bf16x8 __attribute__((ext_vector_type(8)));
typedef float  f32x4v __attribute__((ext_vector_type(4)));

__device__ __forceinline__ float wred_sum(float v){
#pragma unroll
  for (int o=32;o;o>>=1) v += __shfl_xor(v,o,64);
  return v;
}
__device__ __forceinline__ float wred_max(float v){
#pragma unroll
  for (int o=32;o;o>>=1) v = fmaxf(v,__shfl_xor(v,o,64));
  return v;
}
__device__ __forceinline__ unsigned fmono(float f){
  unsigned u = __float_as_uint(f);
  return (u & 0x80000000u) ? ~u : (u | 0x80000000u);
}
__device__ __forceinline__ float sigf(float x){
  return __builtin_amdgcn_rcpf(1.f + __builtin_amdgcn_exp2f(-L2E*x));
}
__device__ __forceinline__ float tanhf2(float x){
  return fmaf(-2.f, __builtin_amdgcn_rcpf(1.f + __builtin_amdgcn_exp2f((2.f*L2E)*x)), 1.f);
}
template<int CTRL>
__device__ __forceinline__ float dpp_add_f(float v){
  int s = __builtin_amdgcn_update_dpp(0, __float_as_int(v), CTRL, 0xF, 0xF, true);
  return v + __int_as_float(s);
}
__device__ __forceinline__ float dpp_red4(float v){
  v = dpp_add_f<0xB1>(v);   // quad_perm [1,0,3,2]  == xor 1
  v = dpp_add_f<0x4E>(v);   // quad_perm [2,3,0,1]  == xor 2
  return v;
}
#if __has_builtin(__builtin_amdgcn_fdot2)
__device__ __forceinline__ float fdot2(half2v a, half2v b, float c){
  return __builtin_amdgcn_fdot2(a, b, c, false);
}
#else
__device__ __forceinline__ float fdot2(half2v a, half2v b, float c){
  return fmaf((float)a[0], (float)b[0], fmaf((float)a[1], (float)b[1], c));
}
#endif
__device__ __forceinline__ half2v pkh2(float a, float b){
  return __builtin_bit_cast(half2v, __builtin_amdgcn_cvt_pkrtz(a, b));
}
__device__ __forceinline__ unsigned short f2bf(float f){
  unsigned u = __float_as_uint(f);
  return (unsigned short)((u + 0x7fffu + ((u>>16)&1u)) >> 16);  // RNE
}
__device__ __forceinline__ f32x4v mfma16(uint4 a, uint4 b, f32x4v c){
  return __builtin_amdgcn_mfma_f32_16x16x32_bf16(
      __builtin_bit_cast(bf16x8, a), __builtin_bit_cast(bf16x8, b), c, 0, 0, 0);
}

// ---------------- MFMA bf16 GEMM: C[m, coff+n] = act(A[M,K] @ W[N,K]^T + b1 + b2)
template<int K>
__global__ __launch_bounds__(256)
void gemm_mfma(const float* __restrict__ A, const float* __restrict__ W,
               const float* __restrict__ b1, const float* __restrict__ b2,
               float* __restrict__ C, int N, int ldc, int coff, int relu)
{
  __shared__ unsigned short As[128][K+8];
  __shared__ unsigned short Ws[64][K+8];
  const int tid = threadIdx.x;
  const int wave = tid >> 6, lane = tid & 63;
  const int ln = lane & 15, kq = lane >> 4;
  const int m0 = blockIdx.y * 128, n0 = blockIdx.x * 64;

  for (int idx = tid; idx < 128*(K/4); idx += 256){
    const int row = idx / (K/4), c4 = idx - row*(K/4);
    const float4 v = *(const float4*)(A + (size_t)(m0+row)*K + c4*4);
    ushort4 s = {f2bf(v.x), f2bf(v.y), f2bf(v.z), f2bf(v.w)};
    *(ushort4*)&As[row][c4*4] = s;
  }
  for (int idx = tid; idx < 64*(K/4); idx += 256){
    const int row = idx / (K/4), c4 = idx - row*(K/4);
    float4 v = {0,0,0,0};
    const int gn = n0 + row;
    if (gn < N) v = *(const float4*)(W + (size_t)gn*K + c4*4);
    ushort4 s = {f2bf(v.x), f2bf(v.y), f2bf(v.z), f2bf(v.w)};
    *(ushort4*)&Ws[row][c4*4] = s;
  }
  __syncthreads();

  f32x4v acc[2][4];
#pragma unroll
  for (int mi=0;mi<2;++mi)
#pragma unroll
    for (int ni=0;ni<4;++ni){ f32x4v z = {0.f,0.f,0.f,0.f}; acc[mi][ni] = z; }

#pragma unroll
  for (int ks=0; ks<K/32; ++ks){
    uint4 af[2], bf[4];
#pragma unroll
    for (int mi=0;mi<2;++mi)
      af[mi] = *(const uint4*)&As[wave*32 + mi*16 + ln][ks*32 + kq*8];
#pragma unroll
    for (int ni=0;ni<4;++ni)
      bf[ni] = *(const uint4*)&Ws[ni*16 + ln][ks*32 + kq*8];
#pragma unroll
    for (int mi=0;mi<2;++mi)
#pragma unroll
      for (int ni=0;ni<4;++ni)
        acc[mi][ni] = mfma16(af[mi], bf[ni], acc[mi][ni]);
  }

#pragma unroll
  for (int ni=0;ni<4;++ni){
    const int gn = n0 + ni*16 + ln;
    if (gn >= N) continue;
    float bias = 0.f;
    if (b1) bias += b1[gn];
    if (b2) bias += b2[gn];
#pragma unroll
    for (int mi=0;mi<2;++mi){
      const int row = m0 + wave*32 + mi*16 + kq*4;
#pragma unroll
      for (int r=0;r<4;++r){
        float v = acc[mi][ni][r] + bias;
        if (relu) v = fmaxf(v, 0.f);
        C[(size_t)(row + r)*ldc + coff + gn] = v;
      }
    }
  }
}

// ---------------- pack qw|kw|vw -> wqkv[288][96]
__global__ __launch_bounds__(256)
void pack_qkv_kernel(const float* __restrict__ qw, const float* __restrict__ kw,
                     const float* __restrict__ vw, float* __restrict__ wqkv)
{
  const int i = blockIdx.x*256 + threadIdx.x;
  if (i < 9216)       wqkv[i] = qw[i];
  else if (i < 18432) wqkv[i] = kw[i-9216];
  else if (i < 27648) wqkv[i] = vw[i-18432];
}

// ---------------- pipelined 2-layer LSTM: blocks 0-15 = layer 0 (producer),
// blocks 16-31 = layer 1 (consumer). Producer = R10 kernel verbatim, publishing
// h0 as fp32 AGENT-scope atomic stores (delayed 1 step; end-of-step barrier's
// vmcnt(0) drain guarantees completion) + release flag every 8 steps. Consumer
// spin-gates (tid0 + s_sleep) every 4 steps with >=6-row margin, agent-scope
// atomic loads of h0 prefetched 2 steps ahead (pfA/pfB concrete names), input
// term via f16 dot2 (>= R11's passing bf16 precision), bias via (q==g) trick.
// No deadlock: producer never waits; 32 blocks always co-resident.
__global__ __launch_bounds__(384, 1)
void lstm_pipe_kernel(const float* __restrict__ pre,
                      const float* __restrict__ w_hh0,
                      const float* __restrict__ w_ih1,
                      const float* __restrict__ w_hh1,
                      const float* __restrict__ b_ih1,
                      const float* __restrict__ b_hh1,
                      float* h0x, int* flag,
                      float* __restrict__ hout)
{
  const int role = blockIdx.x >> 4, b = blockIdx.x & 15;
  const int tid = threadIdx.x;
  const int q = tid & 3, j = tid >> 2;
  __shared__ _Float16 h_lds[96];
  float c = 0.f;
  if (tid < 96) h_lds[tid] = (_Float16)0.f;
  const size_t h0base = (size_t)b * T_SEQ * HID;

  if (role == 0){
    // ---------------- producer: layer 0 (R10 structure)
    half2v w[4][12];
#pragma unroll
    for (int g=0; g<4; ++g){
      const float* wp = w_hh0 + (size_t)(g*96 + j)*96 + q*24;
#pragma unroll
      for (int k=0;k<12;++k){
        half2v t; t[0] = (_Float16)wp[2*k]; t[1] = (_Float16)wp[2*k+1];
        w[g][k] = t;
      }
    }
    __syncthreads();
    const float* prow = pre + (size_t)b*T_SEQ*G4 + q*96 + j;
    float pf[4];
#pragma unroll
    for (int i=0;i<4;++i) pf[i] = prow[(size_t)i*G4];
    float hv_prev = 0.f;

    for (int tb=0; tb<T_SEQ; tb+=4){
#pragma unroll
      for (int u=0; u<4; ++u){
        const int t = tb + u;
        // publish h0[t-1] (fire-and-forget; drained by this step's end barrier)
        if (q == 0 && t > 0)
          __hip_atomic_store(&h0x[h0base + (size_t)(t-1)*HID + j], hv_prev,
                             __ATOMIC_RELAXED, __HIP_MEMORY_SCOPE_AGENT);
        if (tid == 0 && t > 0 && (t & 7) == 0)
          __hip_atomic_store(&flag[b], t-1, __ATOMIC_RELEASE, __HIP_MEMORY_SCOPE_AGENT);
        const float pcur = pf[u];
        int tn = t + 4; if (tn > T_SEQ-1) tn = T_SEQ-1;
        pf[u] = prow[(size_t)tn*G4];
        const uint4 a0 = *(const uint4*)(h_lds + q*24);
        const uint4 a1 = *(const uint4*)(h_lds + q*24 + 8);
        const uint4 a2 = *(const uint4*)(h_lds + q*24 + 16);
        half2v h2[12];
        h2[0]=__builtin_bit_cast(half2v, a0.x); h2[1]=__builtin_bit_cast(half2v, a0.y);
        h2[2]=__builtin_bit_cast(half2v, a0.z); h2[3]=__builtin_bit_cast(half2v, a0.w);
        h2[4]=__builtin_bit_cast(half2v, a1.x); h2[5]=__builtin_bit_cast(half2v, a1.y);
        h2[6]=__builtin_bit_cast(half2v, a1.z); h2[7]=__builtin_bit_cast(half2v, a1.w);
        h2[8]=__builtin_bit_cast(half2v, a2.x); h2[9]=__builtin_bit_cast(half2v, a2.y);
        h2[10]=__builtin_bit_cast(half2v, a2.z); h2[11]=__builtin_bit_cast(half2v, a2.w);
        float sA0=0.f,sA1=0.f,sA2=0.f,sA3=0.f;
        float sB0=0.f,sB1=0.f,sB2=0.f,sB3=0.f;
#pragma unroll
        for (int k=0;k<12;k+=2){
          sA0 = fdot2(w[0][k], h2[k], sA0);  sB0 = fdot2(w[0][k+1], h2[k+1], sB0);
          sA1 = fdot2(w[1][k], h2[k], sA1);  sB1 = fdot2(w[1][k+1], h2[k+1], sB1);
          sA2 = fdot2(w[2][k], h2[k], sA2);  sB2 = fdot2(w[2][k+1], h2[k+1], sB2);
          sA3 = fdot2(w[3][k], h2[k], sA3);  sB3 = fdot2(w[3][k+1], h2[k+1], sB3);
        }
        float s0 = sA0+sB0, s1 = sA1+sB1, s2 = sA2+sB2, s3 = sA3+sB3;
        s0 += (q==0) ? pcur : 0.f;
        s1 += (q==1) ? pcur : 0.f;
        s2 += (q==2) ? pcur : 0.f;
        s3 += (q==3) ? pcur : 0.f;
        s0 = dpp_red4(s0); s1 = dpp_red4(s1);
        s2 = dpp_red4(s2); s3 = dpp_red4(s3);
        const float iv = sigf(s0), fv = sigf(s1);
        const float gv = tanhf2(s2), ov = sigf(s3);
        c = fmaf(fv, c, iv*gv);
        const float hv = ov * tanhf2(c);
        if (q == 0){
          h_lds[j] = (_Float16)hv;
          hv_prev = hv;
        }
        __syncthreads();
      }
    }
    if (q == 0)
      __hip_atomic_store(&h0x[h0base + (size_t)(T_SEQ-1)*HID + j], hv_prev,
                         __ATOMIC_RELAXED, __HIP_MEMORY_SCOPE_AGENT);
    __syncthreads();   // drain final stores
    if (tid == 0)
      __hip_atomic_store(&flag[b], T_SEQ, __ATOMIC_RELEASE, __HIP_MEMORY_SCOPE_AGENT);
  } else {
    // ---------------- consumer: layer 1
    half2v wih[4][12], whh[4][12];
#pragma unroll
    for (int g=0; g<4; ++g){
      const float* wp1 = w_ih1 + (size_t)(g*96 + j)*96 + q*24;
      const float* wp2 = w_hh1 + (size_t)(g*96 + j)*96 + q*24;
#pragma unroll
      for (int k=0;k<12;++k){
        half2v t1; t1[0] = (_Float16)wp1[2*k]; t1[1] = (_Float16)wp1[2*k+1];
        half2v t2; t2[0] = (_Float16)wp2[2*k]; t2[1] = (_Float16)wp2[2*k+1];
        wih[g][k] = t1; whh[g][k] = t2;
      }
    }
    const float biasq = b_ih1[q*96 + j] + b_hh1[q*96 + j];
    float* hrow = hout + (size_t)b*T_SEQ*HID;
    __syncthreads();

#define L1_GATE(NEED)                                                          \
    {                                                                          \
      if (tid == 0){                                                           \
        int f = __hip_atomic_load(&flag[b], __ATOMIC_ACQUIRE,                  \
                                  __HIP_MEMORY_SCOPE_AGENT);                   \
        while (f < (NEED)){                                                    \
          __builtin_amdgcn_s_sleep(8);                                         \
          f = __hip_atomic_load(&flag[b], __ATOMIC_ACQUIRE,                    \
                                __HIP_MEMORY_SCOPE_AGENT);                     \
        }                                                                      \
      }                                                                        \
      __syncthreads();                                                         \
    }

    float pfA[24], pfB[24];
    L1_GATE(6)
#pragma unroll
    for (int k=0;k<24;++k){
      pfA[k] = __hip_atomic_load(&h0x[h0base + 0*HID + q*24 + k],
                                 __ATOMIC_RELAXED, __HIP_MEMORY_SCOPE_AGENT);
      pfB[k] = __hip_atomic_load(&h0x[h0base + 1*HID + q*24 + k],
                                 __ATOMIC_RELAXED, __HIP_MEMORY_SCOPE_AGENT);
    }

#define L1_STEP(T, PF)                                                         \
    {                                                                          \
      half2v g2[12];                                                           \
      _Pragma("unroll")                                                        \
      for (int k=0;k<12;++k) g2[k] = pkh2(PF[2*k], PF[2*k+1]);                 \
      int tp = (T) + 2; if (tp > T_SEQ-1) tp = T_SEQ-1;                        \
      _Pragma("unroll")                                                        \
      for (int k=0;k<24;++k)                                                   \
        PF[k] = __hip_atomic_load(&h0x[h0base + (size_t)tp*HID + q*24 + k],    \
                                  __ATOMIC_RELAXED, __HIP_MEMORY_SCOPE_AGENT); \
      const uint4 a0 = *(const uint4*)(h_lds + q*24);                          \
      const uint4 a1 = *(const uint4*)(h_lds + q*24 + 8);                      \
      const uint4 a2 = *(const uint4*)(h_lds + q*24 + 16);                     \
      half2v h2[12];                                                           \
      h2[0]=__builtin_bit_cast(half2v, a0.x); h2[1]=__builtin_bit_cast(half2v, a0.y); \
      h2[2]=__builtin_bit_cast(half2v, a0.z); h2[3]=__builtin_bit_cast(half2v, a0.w); \
      h2[4]=__builtin_bit_cast(half2v, a1.x); h2[5]=__builtin_bit_cast(half2v, a1.y); \
      h2[6]=__builtin_bit_cast(half2v, a1.z); h2[7]=__builtin_bit_cast(half2v, a1.w); \
      h2[8]=__builtin_bit_cast(half2v, a2.x); h2[9]=__builtin_bit_cast(half2v, a2.y); \
      h2[10]=__builtin_bit_cast(half2v, a2.z); h2[11]=__builtin_bit_cast(half2v, a2.w); \
      float sA0=0.f,sA1=0.f,sA2=0.f,sA3=0.f;                                   \
      float sB0=0.f,sB1=0.f,sB2=0.f,sB3=0.f;                                   \
      _Pragma("unroll")                                                        \
      for (int k=0;k<12;++k){                                                  \
        sA0 = fdot2(wih[0][k], g2[k], sA0);  sB0 = fdot2(whh[0][k], h2[k], sB0); \
        sA1 = fdot2(wih[1][k], g2[k], sA1);  sB1 = fdot2(whh[1][k], h2[k], sB1); \
        sA2 = fdot2(wih[2][k], g2[k], sA2);  sB2 = fdot2(whh[2][k], h2[k], sB2); \
        sA3 = fdot2(wih[3][k], g2[k], sA3);  sB3 = fdot2(whh[3][k], h2[k], sB3); \
      }                                                                        \
      float s0 = sA0+sB0, s1 = sA1+sB1, s2 = sA2+sB2, s3 = sA3+sB3;            \
      s0 += (q==0) ? biasq : 0.f;                                              \
      s1 += (q==1) ? biasq : 0.f;                                              \
      s2 += (q==2) ? biasq : 0.f;                                              \
      s3 += (q==3) ? biasq : 0.f;                                              \
      s0 = dpp_red4(s0); s1 = dpp_red4(s1);                                    \
      s2 = dpp_red4(s2); s3 = dpp_red4(s3);                                    \
      const float iv = sigf(s0), fv = sigf(s1);                                \
      const float gv = tanhf2(s2), ov = sigf(s3);                              \
      c = fmaf(fv, c, iv*gv);                                                  \
      const float hv = ov * tanhf2(c);                                         \
      if (q == 0){                                                             \
        h_lds[j] = (_Float16)hv;                                               \
        hrow[(size_t)(T)*HID + j] = hv;                                        \
      }                                                                        \
      __syncthreads();                                                         \
    }

    for (int tb=0; tb<T_SEQ; tb+=4){
      if (tb > 0){
        const int need = (tb+6 < T_SEQ) ? tb+6 : T_SEQ;
        L1_GATE(need)
      }
      L1_STEP(tb+0, pfA)
      L1_STEP(tb+1, pfB)
      L1_STEP(tb+2, pfA)
      L1_STEP(tb+3, pfB)
    }
#undef L1_STEP
#undef L1_GATE
  }
}

// ---------------- attention, 2 q-rows per wave; f16 dot2 score pass.
__global__ __launch_bounds__(512, 1)
void attn_kernel(const float* __restrict__ qkv, float* __restrict__ out, int sparse)
{
  __shared__ float kl[24][260];
  unsigned* klh = (unsigned*)&kl[0][0];      // aliased [12][260] half2 (pass A)
  const int tid = threadIdx.x;
  const int wave = tid >> 6, lane = tid & 63;
  const int bh = blockIdx.x >> 6;            // 64 blocks per (b,h)
  const int b = bh >> 2, h = bh & 3;
  const int tq = ((blockIdx.x & 63) << 4) + wave*2;   // rows tq, tq+1
  const size_t base = (size_t)b * T_SEQ;
  const int hoff = h * HDIM;
  half2v q20[12], q21[12];
  {
    const float* qp0 = qkv + (base + tq)*QKV_LD + hoff;
    const float* qp1 = qp0 + QKV_LD;
#pragma unroll
    for (int d4=0; d4<6; ++d4){
      float4 t0 = *(const float4*)(qp0 + d4*4);
      float4 t1 = *(const float4*)(qp1 + d4*4);
      q20[d4*2+0] = pkh2(t0.x, t0.y); q20[d4*2+1] = pkh2(t0.z, t0.w);
      q21[d4*2+0] = pkh2(t1.x, t1.y); q21[d4*2+1] = pkh2(t1.z, t1.w);
    }
  }
  float sc0[16], sc1[16];
  for (int c=0;c<4;++c){
    __syncthreads();
#pragma unroll
    for (int rep=0;rep<3;++rep){
      int p = rep*512 + tid;
      int sl = p/6, d4 = p - sl*6;
      const float4 kv = *(const float4*)(qkv + (base + (c<<8) + sl)*QKV_LD + 96 + hoff + d4*4);
      klh[(d4*2+0)*260 + sl] = __builtin_bit_cast(unsigned, pkh2(kv.x, kv.y));
      klh[(d4*2+1)*260 + sl] = __builtin_bit_cast(unsigned, pkh2(kv.z, kv.w));
    }
    __syncthreads();
    float a0=0.f,a1=0.f,a2=0.f,a3=0.f;
    float b0=0.f,b1v=0.f,b2v=0.f,b3=0.f;
#pragma unroll
    for (int dp=0; dp<12; ++dp){
      const uint4 kd = *(const uint4*)&klh[dp*260 + lane*4];
      const half2v k0 = __builtin_bit_cast(half2v, kd.x);
      const half2v k1 = __builtin_bit_cast(half2v, kd.y);
      const half2v k2 = __builtin_bit_cast(half2v, kd.z);
      const half2v k3 = __builtin_bit_cast(half2v, kd.w);
      a0 = fdot2(q20[dp], k0, a0); a1 = fdot2(q20[dp], k1, a1);
      a2 = fdot2(q20[dp], k2, a2); a3 = fdot2(q20[dp], k3, a3);
      b0 = fdot2(q21[dp], k0, b0); b1v = fdot2(q21[dp], k1, b1v);
      b2v = fdot2(q21[dp], k2, b2v); b3 = fdot2(q21[dp], k3, b3);
    }
    sc0[c*4+0]=a0*SCALE; sc0[c*4+1]=a1*SCALE; sc0[c*4+2]=a2*SCALE; sc0[c*4+3]=a3*SCALE;
    sc1[c*4+0]=b0*SCALE; sc1[c*4+1]=b1v*SCALE; sc1[c*4+2]=b2v*SCALE; sc1[c*4+3]=b3*SCALE;
  }
  float inv0, inv1;
#define SOFTMAX_ROW(SC, INV)                                                  \
  {                                                                           \
    float m_loc = SC[0];                                                      \
    _Pragma("unroll")                                                         \
    for (int i=1;i<16;++i) m_loc = fmaxf(m_loc, SC[i]);                       \
    const float m = wred_max(m_loc);                                          \
    float sum_loc = 0.f;                                                      \
    if (sparse){                                                              \
      unsigned u[16];                                                         \
      _Pragma("unroll")                                                       \
      for (int i=0;i<16;++i) u[i] = fmono(SC[i]);                             \
      unsigned prefix = 0;                                                    \
      for (int bit=31; bit>=0; --bit){                                        \
        const unsigned test = prefix | (1u<<bit);                             \
        int cnt = 0;                                                          \
        _Pragma("unroll")                                                     \
        for (int i=0;i<16;++i)                                                \
          cnt += (int)__popcll(__ballot(u[i] >= test));                       \
        if (cnt >= KKEEP) prefix = test;                                      \
      }                                                                       \
      _Pragma("unroll")                                                       \
      for (int i=0;i<16;++i){                                                 \
        float e = (u[i] >= prefix) ? __expf(SC[i]-m) : 0.f;                   \
        SC[i] = e; sum_loc += e;                                              \
      }                                                                       \
    } else {                                                                  \
      _Pragma("unroll")                                                       \
      for (int i=0;i<16;++i){                                                 \
        float e = __expf(SC[i]-m);                                            \
        SC[i] = e; sum_loc += e;                                              \
      }                                                                       \
    }                                                                         \
    INV = 1.f / wred_sum(sum_loc);                                            \
  }
  SOFTMAX_ROW(sc0, inv0)
  SOFTMAX_ROW(sc1, inv1)
#undef SOFTMAX_ROW
#pragma unroll
  for (int i=0;i<16;++i){ sc0[i] *= inv0; sc1[i] *= inv1; }
  float acc0[24] = {}, acc1[24] = {};
  for (int c=0;c<4;++c){
    __syncthreads();
#pragma unroll
    for (int rep=0;rep<3;++rep){
      int p = rep*512 + tid;
      int sl = p/6, d4 = p - sl*6;
      const float4 vv = *(const float4*)(qkv + (base + (c<<8) + sl)*QKV_LD + 192 + hoff + d4*4);
      kl[d4*4+0][sl]=vv.x; kl[d4*4+1][sl]=vv.y; kl[d4*4+2][sl]=vv.z; kl[d4*4+3][sl]=vv.w;
    }
    __syncthreads();
    const float w00=sc0[c*4], w01=sc0[c*4+1], w02=sc0[c*4+2], w03=sc0[c*4+3];
    const float w10=sc1[c*4], w11=sc1[c*4+1], w12=sc1[c*4+2], w13=sc1[c*4+3];
#pragma unroll
    for (int d=0; d<24; ++d){
      const float4 vd = *(const float4*)&kl[d][lane*4];
      acc0[d] += w00*vd.x + w01*vd.y + w02*vd.z + w03*vd.w;
      acc1[d] += w10*vd.x + w11*vd.y + w12*vd.z + w13*vd.w;
    }
  }
#pragma unroll
  for (int d=0; d<24; ++d){ acc0[d] = wred_sum(acc0[d]); acc1[d] = wred_sum(acc1[d]); }
  if (lane == 0){
    float* op0 = out + (base + tq)*HID + hoff;
    float* op1 = op0 + HID;
#pragma unroll
    for (int d4=0; d4<6; ++d4){
      float4 t0 = {acc0[d4*4], acc0[d4*4+1], acc0[d4*4+2], acc0[d4*4+3]};
      float4 t1 = {acc1[d4*4], acc1[d4*4+1], acc1[d4*4+2], acc1[d4*4+3]};
      *(float4*)(op0 + d4*4) = t0;
      *(float4*)(op1 + d4*4) = t1;
    }
  }
}

// ---------------- dense attention for t = T-1 only (encoder 2)
__global__ __launch_bounds__(64)
void attn_last_kernel(const float* __restrict__ qkv, float* __restrict__ out)
{
  const int bh = blockIdx.x, b = bh>>2, h = bh&3;
  const int lane = threadIdx.x;
  const size_t base = (size_t)b*T_SEQ;
  const int hoff = h*HDIM;
  float q[24];
  {
    const float* qp = qkv + (base + T_SEQ-1)*QKV_LD + hoff;
#pragma unroll
    for (int d4=0; d4<6; ++d4){
      float4 t = *(const float4*)(qp + d4*4);
      q[d4*4]=t.x; q[d4*4+1]=t.y; q[d4*4+2]=t.z; q[d4*4+3]=t.w;
    }
  }
  float sc[16];
#pragma unroll 4
  for (int i=0;i<16;++i){
    const float* kp = qkv + (base + i*64 + lane)*QKV_LD + 96 + hoff;
    float a = 0.f;
#pragma unroll
    for (int d4=0; d4<6; ++d4){
      float4 kv = *(const float4*)(kp + d4*4);
      a += q[d4*4]*kv.x + q[d4*4+1]*kv.y + q[d4*4+2]*kv.z + q[d4*4+3]*kv.w;
    }
    sc[i] = a*SCALE;
  }
  float m_loc = sc[0];
#pragma unroll
  for (int i=1;i<16;++i) m_loc = fmaxf(m_loc, sc[i]);
  const float m = wred_max(m_loc);
  float sum_loc = 0.f;
#pragma unroll
  for (int i=0;i<16;++i){ sc[i] = __expf(sc[i]-m); sum_loc += sc[i]; }
  const float inv = 1.f / wred_sum(sum_loc);
  float acc[24] = {};
#pragma unroll 4
  for (int i=0;i<16;++i){
    const float* vp = qkv + (base + i*64 + lane)*QKV_LD + 192 + hoff;
    const float wgt = sc[i]*inv;
#pragma unroll
    for (int d4=0; d4<6; ++d4){
      float4 vv = *(const float4*)(vp + d4*4);
      acc[d4*4]   += wgt*vv.x; acc[d4*4+1] += wgt*vv.y;
      acc[d4*4+2] += wgt*vv.z; acc[d4*4+3] += wgt*vv.w;
    }
  }
#pragma unroll
  for (int d=0; d<24; ++d) acc[d] = wred_sum(acc[d]);
  if (lane == 0){
    float* op = out + (base + T_SEQ-1)*HID + hoff;
#pragma unroll
    for (int d4=0; d4<6; ++d4){
      float4 t = {acc[d4*4], acc[d4*4+1], acc[d4*4+2], acc[d4*4+3]};
      *(float4*)(op + d4*4) = t;
    }
  }
}

// ---------------- out = LayerNorm(x + y) * w + b ; one wave per 96-wide row
__global__ __launch_bounds__(256)
void resln_kernel(const float* __restrict__ x, const float* __restrict__ y,
                  const float* __restrict__ w, const float* __restrict__ bb,
                  float* __restrict__ out)
{
  const int row = blockIdx.x*4 + (threadIdx.x>>6);
  const int lane = threadIdx.x & 63;
  const float* xr = x + (size_t)row*HID;
  const float* yr = y + (size_t)row*HID;
  float v0 = xr[lane] + yr[lane];
  float v1 = (lane < 32) ? (xr[64+lane] + yr[64+lane]) : 0.f;
  float mu = wred_sum(v0+v1) * (1.f/96.f);
  float d0 = v0-mu, d1 = (lane<32) ? (v1-mu) : 0.f;
  float var = wred_sum(d0*d0 + d1*d1) * (1.f/96.f);
  float rs = rsqrtf(var + 1e-5f);
  float* orow = out + (size_t)row*HID;
  orow[lane] = d0*rs*w[lane] + bb[lane];
  if (lane < 32) orow[64+lane] = d1*rs*w[64+lane] + bb[64+lane];
}

// ---------------- encoder-2 tail at t=T-1 only: proj+LN1+FF+LN2+fc
__device__ __forceinline__ float block_sum_192(float v, float* red){
  v = wred_sum(v);
  const int tid = threadIdx.x;
  if ((tid & 63) == 0) red[tid>>6] = v;
  __syncthreads();
  float r = red[0]+red[1]+red[2];
  __syncthreads();
  return r;
}

__global__ __launch_bounds__(192)
void tail_kernel(const float* __restrict__ xin, const float* __restrict__ mha,
                 const float* __restrict__ out_w, const float* __restrict__ out_b,
                 const float* __restrict__ l1_w, const float* __restrict__ l1_b,
                 const float* __restrict__ l2_w, const float* __restrict__ l2_b,
                 const float* __restrict__ ln1w, const float* __restrict__ ln1b,
                 const float* __restrict__ ln2w, const float* __restrict__ ln2b,
                 const float* __restrict__ fcw, const float* __restrict__ fcb,
                 float* __restrict__ outp)
{
  const int b = blockIdx.x, tid = threadIdx.x;
  __shared__ float y[96], f1[192], mrow[96], red[3];
  const size_t row = ((size_t)b*T_SEQ + T_SEQ-1)*HID;
  if (tid < 96) mrow[tid] = mha[row + tid];
  __syncthreads();
  float r = 0.f;
  if (tid < 96){
    float p = out_b[tid];
    const float* wr = out_w + tid*96;
#pragma unroll 4
    for (int d=0; d<96; ++d) p += mrow[d]*wr[d];
    r = xin[row + tid] + p;
  }
  float mu = block_sum_192(tid<96 ? r : 0.f, red) * (1.f/96.f);
  float dv = tid<96 ? r-mu : 0.f;
  float var = block_sum_192(dv*dv, red) * (1.f/96.f);
  float rs = rsqrtf(var + 1e-5f);
  if (tid < 96) y[tid] = dv*rs*ln1w[tid] + ln1b[tid];
  __syncthreads();
  {
    float a = l1_b[tid];
    const float* wr = l1_w + tid*96;
#pragma unroll 4
    for (int d=0; d<96; ++d) a += y[d]*wr[d];
    f1[tid] = fmaxf(a, 0.f);
  }
  __syncthreads();
  float r2 = 0.f;
  if (tid < 96){
    float a = l2_b[tid];
    const float* wr = l2_w + tid*192;
#pragma unroll 4
    for (int d=0; d<192; ++d) a += f1[d]*wr[d];
    r2 = y[tid] + a;
  }
  float mu2 = block_sum_192(tid<96 ? r2 : 0.f, red) * (1.f/96.f);
  float dv2 = tid<96 ? r2-mu2 : 0.f;
  float var2 = block_sum_192(dv2*dv2, red) * (1.f/96.f);
  float rs2 = rsqrtf(var2 + 1e-5f);
  float z = tid<96 ? (dv2*rs2*ln2w[tid] + ln2b[tid]) : 0.f;
  float tot = block_sum_192(tid<96 ? z*fcw[tid] : 0.f, red);
  if (tid == 0) outp[b] = tot + fcb[0];
}

extern "C" void kernel_launch(void* const* d_in, const int* in_sizes, int n_in,
                              void* d_out, int out_size, void* d_ws, size_t ws_size,
                              hipStream_t stream)
{
  const float* x     = (const float*)d_in[0];
  const float* w_ih0 = (const float*)d_in[1];
  const float* w_hh0 = (const float*)d_in[2];
  const float* b_ih0 = (const float*)d_in[3];
  const float* b_hh0 = (const float*)d_in[4];
  const float* w_ih1 = (const float*)d_in[5];
  const float* w_hh1 = (const float*)d_in[6];
  const float* b_ih1 = (const float*)d_in[7];
  const float* b_hh1 = (const float*)d_in[8];
  const float* qw = (const float*)d_in[9];
  const float* kw = (const float*)d_in[10];
  const float* vw = (const float*)d_in[11];
  const float* ow = (const float*)d_in[12];
  const float* enc_in_w  = (const float*)d_in[13];
  const float* enc_in_b  = (const float*)d_in[14];
  const float* enc_out_w = (const float*)d_in[15];
  const float* enc_out_b = (const float*)d_in[16];
  const float* enc_l1_w  = (const float*)d_in[17];
  const float* enc_l1_b  = (const float*)d_in[18];
  const float* enc_l2_w  = (const float*)d_in[19];
  const float* enc_l2_b  = (const float*)d_in[20];
  const float* enc_ln1_w = (const float*)d_in[21];
  const float* enc_ln1_b = (const float*)d_in[22];
  const float* enc_ln2_w = (const float*)d_in[23];
  const float* enc_ln2_b = (const float*)d_in[24];
  const float* fc_w = (const float*)d_in[25];
  const float* fc_b = (const float*)d_in[26];
  float* outp = (float*)d_out;

  float* ws = (float*)d_ws;
  const size_t MT = (size_t)BATCH*T_SEQ;   // 16384
  float* pre  = ws;                        // 16384*384 (also qkv[288] / ff1[192])
  float* bufA = pre  + MT*G4;              // h0x during LSTM; attn out later
  float* bufB = bufA + MT*HID;
  float* bufC = bufB + MT*HID;
  float* wqkv = bufC + MT*HID;             // 288*96 packed qkv weights
  int*   flag = (int*)(wqkv + 27648);      // 16 ints, reset each launch

  auto gemm = [&](const float* A, const float* W, const float* bb1, const float* bb2,
                  float* C, int N, int K, int ldc, int coff, int relu){
    dim3 grid((N+63)/64, 128);
    if (K == 64)
      gemm_mfma<64><<<grid, dim3(256), 0, stream>>>(A, W, bb1, bb2, C, N, ldc, coff, relu);
    else if (K == 96)
      gemm_mfma<96><<<grid, dim3(256), 0, stream>>>(A, W, bb1, bb2, C, N, ldc, coff, relu);
    else
      gemm_mfma<192><<<grid, dim3(256), 0, stream>>>(A, W, bb1, bb2, C, N, ldc, coff, relu);
  };

  hipMemsetAsync(flag, 0, 16*sizeof(int), stream);
  pack_qkv_kernel<<<dim3(108), dim3(256), 0, stream>>>(qw, kw, vw, wqkv);

  // LSTM stack: layer-0 input GEMM, then both layers pipelined across CUs
  gemm(x, w_ih0, b_ih0, b_hh0, pre, 384, 64, 384, 0, 0);
  lstm_pipe_kernel<<<dim3(32), dim3(384), 0, stream>>>(
      pre, w_hh0, w_ih1, w_hh1, b_ih1, b_hh1, bufA, flag, bufB);
  // sparse attention (fused qkv GEMM via packed weights)
  gemm(bufB, wqkv, nullptr, nullptr, pre, 288, 96, QKV_LD, 0, 0);
  attn_kernel<<<dim3(4096), dim3(512), 0, stream>>>(pre, bufA, 1);
  gemm(bufA, ow, nullptr, nullptr, bufB, 96, 96, 96, 0, 0);
  // encoder layer 0 (full)
  gemm(bufB, enc_in_w, enc_in_b, nullptr, pre, 288, 96, QKV_LD, 0, 0);
  attn_kernel<<<dim3(4096), dim3(512), 0, stream>>>(pre, bufA, 0);
  gemm(bufA, enc_out_w, enc_out_b, nullptr, bufC, 96, 96, 96, 0, 0);
  resln_kernel<<<dim3(4096), dim3(256), 0, stream>>>(bufB, bufC, enc_ln1_w, enc_ln1_b, bufB);
  gemm(bufB, enc_l1_w, enc_l1_b, nullptr, pre, 192, 96, 192, 0, 1);
  gemm(pre, enc_l2_w, enc_l2_b, nullptr, bufC, 96, 192, 96, 0, 0);
  resln_kernel<<<dim3(4096), dim3(256), 0, stream>>>(bufB, bufC, enc_ln2_w, enc_ln2_b, bufB);
  // encoder layer 1 — only t = T-1 reaches the output head
  gemm(bufB, enc_in_w + 288*96, enc_in_b + 288, nullptr, pre, 288, 96, QKV_LD, 0, 0);
  attn_last_kernel<<<dim3(64), dim3(64), 0, stream>>>(pre, bufA);
  tail_kernel<<<dim3(BATCH), dim3(192), 0, stream>>>(
      bufB, bufA,
      enc_out_w + 96*96, enc_out_b + 96,
      enc_l1_w + 192*96, enc_l1_b + 192,
      enc_l2_w + 96*192, enc_l2_b + 96,
      enc_ln1_w + 96, enc_ln1_b + 96,
      enc_ln2_w + 96, enc_ln2_b + 96,
      fc_w, fc_b, outp);
}

// Round 20
// 1813.804 us; speedup vs baseline: 1.1642x; 1.1642x over previous
//
#include <hip/hip_runtime.h>
#include <cstdint>
#include <cmath>

#define T_SEQ 1024
#define BATCH 16
#define HID 96
#define G4 384
#define QKV_LD 288
#define HDIM 24
#define KKEEP 512
#define SCALE 0.20412414523193154f  // 1/sqrt(24)
#define L2E 1.4426950408889634f     // log2(e)

typedef _Float16 half2v __attribute__((ext_vector_type(2)));
typedef __bf16 bf16x8 __attribute__((ext_vector_type(8)));
typedef float  f32x4v __attribute__((ext_vector_type(4)));

__device__ __forceinline__ float wred_sum(float v){
#pragma unroll
  for (int o=32;o;o>>=1) v += __shfl_xor(v,o,64);
  return v;
}
__device__ __forceinline__ float wred_max(float v){
#pragma unroll
  for (int o=32;o;o>>=1) v = fmaxf(v,__shfl_xor(v,o,64));
  return v;
}
__device__ __forceinline__ unsigned fmono(float f){
  unsigned u = __float_as_uint(f);
  return (u & 0x80000000u) ? ~u : (u | 0x80000000u);
}
__device__ __forceinline__ float sigf(float x){
  return __builtin_amdgcn_rcpf(1.f + __builtin_amdgcn_exp2f(-L2E*x));
}
__device__ __forceinline__ float tanhf2(float x){
  return fmaf(-2.f, __builtin_amdgcn_rcpf(1.f + __builtin_amdgcn_exp2f((2.f*L2E)*x)), 1.f);
}
template<int CTRL>
__device__ __forceinline__ float dpp_add_f(float v){
  int s = __builtin_amdgcn_update_dpp(0, __float_as_int(v), CTRL, 0xF, 0xF, true);
  return v + __int_as_float(s);
}
__device__ __forceinline__ float dpp_red4(float v){
  v = dpp_add_f<0xB1>(v);   // quad_perm [1,0,3,2]  == xor 1
  v = dpp_add_f<0x4E>(v);   // quad_perm [2,3,0,1]  == xor 2
  return v;
}
#if __has_builtin(__builtin_amdgcn_fdot2)
__device__ __forceinline__ float fdot2(half2v a, half2v b, float c){
  return __builtin_amdgcn_fdot2(a, b, c, false);
}
#else
__device__ __forceinline__ float fdot2(half2v a, half2v b, float c){
  return fmaf((float)a[0], (float)b[0], fmaf((float)a[1], (float)b[1], c));
}
#endif
__device__ __forceinline__ half2v pkh2(float a, float b){
  return __builtin_bit_cast(half2v, __builtin_amdgcn_cvt_pkrtz(a, b));
}
__device__ __forceinline__ unsigned short f2bf(float f){
  unsigned u = __float_as_uint(f);
  return (unsigned short)((u + 0x7fffu + ((u>>16)&1u)) >> 16);  // RNE
}
__device__ __forceinline__ f32x4v mfma16(uint4 a, uint4 b, f32x4v c){
  return __builtin_amdgcn_mfma_f32_16x16x32_bf16(
      __builtin_bit_cast(bf16x8, a), __builtin_bit_cast(bf16x8, b), c, 0, 0, 0);
}

// ---------------- MFMA bf16 GEMM: C[m, coff+n] = act(A[M,K] @ W[N,K]^T + b1 + b2)
template<int K>
__global__ __launch_bounds__(256)
void gemm_mfma(const float* __restrict__ A, const float* __restrict__ W,
               const float* __restrict__ b1, const float* __restrict__ b2,
               float* __restrict__ C, int N, int ldc, int coff, int relu)
{
  __shared__ unsigned short As[128][K+8];
  __shared__ unsigned short Ws[64][K+8];
  const int tid = threadIdx.x;
  const int wave = tid >> 6, lane = tid & 63;
  const int ln = lane & 15, kq = lane >> 4;
  const int m0 = blockIdx.y * 128, n0 = blockIdx.x * 64;

  for (int idx = tid; idx < 128*(K/4); idx += 256){
    const int row = idx / (K/4), c4 = idx - row*(K/4);
    const float4 v = *(const float4*)(A + (size_t)(m0+row)*K + c4*4);
    ushort4 s = {f2bf(v.x), f2bf(v.y), f2bf(v.z), f2bf(v.w)};
    *(ushort4*)&As[row][c4*4] = s;
  }
  for (int idx = tid; idx < 64*(K/4); idx += 256){
    const int row = idx / (K/4), c4 = idx - row*(K/4);
    float4 v = {0,0,0,0};
    const int gn = n0 + row;
    if (gn < N) v = *(const float4*)(W + (size_t)gn*K + c4*4);
    ushort4 s = {f2bf(v.x), f2bf(v.y), f2bf(v.z), f2bf(v.w)};
    *(ushort4*)&Ws[row][c4*4] = s;
  }
  __syncthreads();

  f32x4v acc[2][4];
#pragma unroll
  for (int mi=0;mi<2;++mi)
#pragma unroll
    for (int ni=0;ni<4;++ni){ f32x4v z = {0.f,0.f,0.f,0.f}; acc[mi][ni] = z; }

#pragma unroll
  for (int ks=0; ks<K/32; ++ks){
    uint4 af[2], bf[4];
#pragma unroll
    for (int mi=0;mi<2;++mi)
      af[mi] = *(const uint4*)&As[wave*32 + mi*16 + ln][ks*32 + kq*8];
#pragma unroll
    for (int ni=0;ni<4;++ni)
      bf[ni] = *(const uint4*)&Ws[ni*16 + ln][ks*32 + kq*8];
#pragma unroll
    for (int mi=0;mi<2;++mi)
#pragma unroll
      for (int ni=0;ni<4;++ni)
        acc[mi][ni] = mfma16(af[mi], bf[ni], acc[mi][ni]);
  }

#pragma unroll
  for (int ni=0;ni<4;++ni){
    const int gn = n0 + ni*16 + ln;
    if (gn >= N) continue;
    float bias = 0.f;
    if (b1) bias += b1[gn];
    if (b2) bias += b2[gn];
#pragma unroll
    for (int mi=0;mi<2;++mi){
      const int row = m0 + wave*32 + mi*16 + kq*4;
#pragma unroll
      for (int r=0;r<4;++r){
        float v = acc[mi][ni][r] + bias;
        if (relu) v = fmaxf(v, 0.f);
        C[(size_t)(row + r)*ldc + coff + gn] = v;
      }
    }
  }
}

// ---------------- pack qw|kw|vw -> wqkv[288][96]
__global__ __launch_bounds__(256)
void pack_qkv_kernel(const float* __restrict__ qw, const float* __restrict__ kw,
                     const float* __restrict__ vw, float* __restrict__ wqkv)
{
  const int i = blockIdx.x*256 + threadIdx.x;
  if (i < 9216)       wqkv[i] = qw[i];
  else if (i < 18432) wqkv[i] = kw[i-9216];
  else if (i < 27648) wqkv[i] = vw[i-18432];
}

// ---------------- sequential LSTM, 1 barrier per step, f16 dot2 matvec.
// DELAYED global h-store: hv kept in a register and written at the TOP of the
// NEXT step, so the store has a full step (~1200cy) to complete before the
// barrier's vmcnt(0) drain (was issued right before the barrier -> full
// HBM/L2 store-ack latency exposed on the critical chain every step).
__global__ __launch_bounds__(384)
void lstm_kernel(const float* __restrict__ pre, const float* __restrict__ w_hh,
                 float* __restrict__ hout)
{
  const int b = blockIdx.x;
  const int tid = threadIdx.x;
  const int q = tid & 3, j = tid >> 2;
  half2v w[4][12];
#pragma unroll
  for (int g=0; g<4; ++g){
    const float* wp = w_hh + (size_t)(g*96 + j)*96 + q*24;
#pragma unroll
    for (int k=0;k<12;++k){
      half2v t; t[0] = (_Float16)wp[2*k]; t[1] = (_Float16)wp[2*k+1];
      w[g][k] = t;
    }
  }
  __shared__ _Float16 h_lds[96];
  float c = 0.f;
  if (tid < 96) h_lds[tid] = (_Float16)0.f;
  __syncthreads();

  const float* prow = pre + (size_t)b*T_SEQ*G4 + q*96 + j;
  float* hrow = hout + (size_t)b*T_SEQ*HID;
  float pf[4];
#pragma unroll
  for (int i=0;i<4;++i) pf[i] = prow[(size_t)i*G4];
  float hv_prev = 0.f;

  for (int tb=0; tb<T_SEQ; tb+=4){
#pragma unroll
    for (int u=0; u<4; ++u){
      const int t = tb + u;
      if (q == 0 && t > 0)
        hrow[(size_t)(t-1)*HID + j] = hv_prev;   // delayed store: hides ack latency
      const float pcur = pf[u];
      int tn = t + 4; if (tn > T_SEQ-1) tn = T_SEQ-1;
      pf[u] = prow[(size_t)tn*G4];               // prefetch 4 steps ahead
      const uint4 a0 = *(const uint4*)(h_lds + q*24);
      const uint4 a1 = *(const uint4*)(h_lds + q*24 + 8);
      const uint4 a2 = *(const uint4*)(h_lds + q*24 + 16);
      half2v h2[12];
      h2[0]=__builtin_bit_cast(half2v, a0.x); h2[1]=__builtin_bit_cast(half2v, a0.y);
      h2[2]=__builtin_bit_cast(half2v, a0.z); h2[3]=__builtin_bit_cast(half2v, a0.w);
      h2[4]=__builtin_bit_cast(half2v, a1.x); h2[5]=__builtin_bit_cast(half2v, a1.y);
      h2[6]=__builtin_bit_cast(half2v, a1.z); h2[7]=__builtin_bit_cast(half2v, a1.w);
      h2[8]=__builtin_bit_cast(half2v, a2.x); h2[9]=__builtin_bit_cast(half2v, a2.y);
      h2[10]=__builtin_bit_cast(half2v, a2.z); h2[11]=__builtin_bit_cast(half2v, a2.w);

      float sA0=0.f,sA1=0.f,sA2=0.f,sA3=0.f;
      float sB0=0.f,sB1=0.f,sB2=0.f,sB3=0.f;
#pragma unroll
      for (int k=0;k<12;k+=2){
        sA0 = fdot2(w[0][k], h2[k], sA0);  sB0 = fdot2(w[0][k+1], h2[k+1], sB0);
        sA1 = fdot2(w[1][k], h2[k], sA1);  sB1 = fdot2(w[1][k+1], h2[k+1], sB1);
        sA2 = fdot2(w[2][k], h2[k], sA2);  sB2 = fdot2(w[2][k+1], h2[k+1], sB2);
        sA3 = fdot2(w[3][k], h2[k], sA3);  sB3 = fdot2(w[3][k+1], h2[k+1], sB3);
      }
      float s0 = sA0+sB0, s1 = sA1+sB1, s2 = sA2+sB2, s3 = sA3+sB3;
      s0 += (q==0) ? pcur : 0.f;
      s1 += (q==1) ? pcur : 0.f;
      s2 += (q==2) ? pcur : 0.f;
      s3 += (q==3) ? pcur : 0.f;
      s0 = dpp_red4(s0);
      s1 = dpp_red4(s1);
      s2 = dpp_red4(s2);
      s3 = dpp_red4(s3);
      const float iv = sigf(s0), fv = sigf(s1);
      const float gv = tanhf2(s2), ov = sigf(s3);
      c = fmaf(fv, c, iv*gv);
      const float hv = ov * tanhf2(c);
      if (q == 0){
        h_lds[j] = (_Float16)hv;
        hv_prev = hv;
      }
      __syncthreads();
    }
  }
  if (q == 0)
    hrow[(size_t)(T_SEQ-1)*HID + j] = hv_prev;
}

// ---------------- attention, 2 q-rows per wave; f16 dot2 score pass.
// qkv layout: [B*T][288] (q|k|v). Block = 8 waves x 2 rows = 16 q rows.
// Pass A: K staged as half2 (cvt_pkrtz during staging); Q held as 12 half2
// regs; scores via fdot2. Pass B (PV) fp32. Softmax via macro on concrete
// array names (no runtime pointer-select -> no scratch spill).
__global__ __launch_bounds__(512, 1)
void attn_kernel(const float* __restrict__ qkv, float* __restrict__ out, int sparse)
{
  __shared__ float kl[24][260];
  unsigned* klh = (unsigned*)&kl[0][0];      // aliased [12][260] half2 (pass A)
  const int tid = threadIdx.x;
  const int wave = tid >> 6, lane = tid & 63;
  const int bh = blockIdx.x >> 6;            // 64 blocks per (b,h)
  const int b = bh >> 2, h = bh & 3;
  const int tq = ((blockIdx.x & 63) << 4) + wave*2;   // rows tq, tq+1
  const size_t base = (size_t)b * T_SEQ;
  const int hoff = h * HDIM;
  half2v q20[12], q21[12];
  {
    const float* qp0 = qkv + (base + tq)*QKV_LD + hoff;
    const float* qp1 = qp0 + QKV_LD;
#pragma unroll
    for (int d4=0; d4<6; ++d4){
      float4 t0 = *(const float4*)(qp0 + d4*4);
      float4 t1 = *(const float4*)(qp1 + d4*4);
      q20[d4*2+0] = pkh2(t0.x, t0.y); q20[d4*2+1] = pkh2(t0.z, t0.w);
      q21[d4*2+0] = pkh2(t1.x, t1.y); q21[d4*2+1] = pkh2(t1.z, t1.w);
    }
  }
  float sc0[16], sc1[16];
  for (int c=0;c<4;++c){
    __syncthreads();
#pragma unroll
    for (int rep=0;rep<3;++rep){
      int p = rep*512 + tid;
      int sl = p/6, d4 = p - sl*6;
      const float4 kv = *(const float4*)(qkv + (base + (c<<8) + sl)*QKV_LD + 96 + hoff + d4*4);
      klh[(d4*2+0)*260 + sl] = __builtin_bit_cast(unsigned, pkh2(kv.x, kv.y));
      klh[(d4*2+1)*260 + sl] = __builtin_bit_cast(unsigned, pkh2(kv.z, kv.w));
    }
    __syncthreads();
    float a0=0.f,a1=0.f,a2=0.f,a3=0.f;
    float b0=0.f,b1v=0.f,b2v=0.f,b3=0.f;
#pragma unroll
    for (int dp=0; dp<12; ++dp){
      const uint4 kd = *(const uint4*)&klh[dp*260 + lane*4];
      const half2v k0 = __builtin_bit_cast(half2v, kd.x);
      const half2v k1 = __builtin_bit_cast(half2v, kd.y);
      const half2v k2 = __builtin_bit_cast(half2v, kd.z);
      const half2v k3 = __builtin_bit_cast(half2v, kd.w);
      a0 = fdot2(q20[dp], k0, a0); a1 = fdot2(q20[dp], k1, a1);
      a2 = fdot2(q20[dp], k2, a2); a3 = fdot2(q20[dp], k3, a3);
      b0 = fdot2(q21[dp], k0, b0); b1v = fdot2(q21[dp], k1, b1v);
      b2v = fdot2(q21[dp], k2, b2v); b3 = fdot2(q21[dp], k3, b3);
    }
    sc0[c*4+0]=a0*SCALE; sc0[c*4+1]=a1*SCALE; sc0[c*4+2]=a2*SCALE; sc0[c*4+3]=a3*SCALE;
    sc1[c*4+0]=b0*SCALE; sc1[c*4+1]=b1v*SCALE; sc1[c*4+2]=b2v*SCALE; sc1[c*4+3]=b3*SCALE;
  }
  float inv0, inv1;
#define SOFTMAX_ROW(SC, INV)                                                  \
  {                                                                           \
    float m_loc = SC[0];                                                      \
    _Pragma("unroll")                                                         \
    for (int i=1;i<16;++i) m_loc = fmaxf(m_loc, SC[i]);                       \
    const float m = wred_max(m_loc);                                          \
    float sum_loc = 0.f;                                                      \
    if (sparse){                                                              \
      unsigned u[16];                                                         \
      _Pragma("unroll")                                                       \
      for (int i=0;i<16;++i) u[i] = fmono(SC[i]);                             \
      unsigned prefix = 0;                                                    \
      for (int bit=31; bit>=0; --bit){                                        \
        const unsigned test = prefix | (1u<<bit);                             \
        int cnt = 0;                                                          \
        _Pragma("unroll")                                                     \
        for (int i=0;i<16;++i)                                                \
          cnt += (int)__popcll(__ballot(u[i] >= test));                       \
        if (cnt >= KKEEP) prefix = test;                                      \
      }                                                                       \
      _Pragma("unroll")                                                       \
      for (int i=0;i<16;++i){                                                 \
        float e = (u[i] >= prefix) ? __expf(SC[i]-m) : 0.f;                   \
        SC[i] = e; sum_loc += e;                                              \
      }                                                                       \
    } else {                                                                  \
      _Pragma("unroll")                                                       \
      for (int i=0;i<16;++i){                                                 \
        float e = __expf(SC[i]-m);                                            \
        SC[i] = e; sum_loc += e;                                              \
      }                                                                       \
    }                                                                         \
    INV = 1.f / wred_sum(sum_loc);                                            \
  }
  SOFTMAX_ROW(sc0, inv0)
  SOFTMAX_ROW(sc1, inv1)
#undef SOFTMAX_ROW
#pragma unroll
  for (int i=0;i<16;++i){ sc0[i] *= inv0; sc1[i] *= inv1; }
  float acc0[24] = {}, acc1[24] = {};
  for (int c=0;c<4;++c){
    __syncthreads();
#pragma unroll
    for (int rep=0;rep<3;++rep){
      int p = rep*512 + tid;
      int sl = p/6, d4 = p - sl*6;
      const float4 vv = *(const float4*)(qkv + (base + (c<<8) + sl)*QKV_LD + 192 + hoff + d4*4);
      kl[d4*4+0][sl]=vv.x; kl[d4*4+1][sl]=vv.y; kl[d4*4+2][sl]=vv.z; kl[d4*4+3][sl]=vv.w;
    }
    __syncthreads();
    const float w00=sc0[c*4], w01=sc0[c*4+1], w02=sc0[c*4+2], w03=sc0[c*4+3];
    const float w10=sc1[c*4], w11=sc1[c*4+1], w12=sc1[c*4+2], w13=sc1[c*4+3];
#pragma unroll
    for (int d=0; d<24; ++d){
      const float4 vd = *(const float4*)&kl[d][lane*4];
      acc0[d] += w00*vd.x + w01*vd.y + w02*vd.z + w03*vd.w;
      acc1[d] += w10*vd.x + w11*vd.y + w12*vd.z + w13*vd.w;
    }
  }
#pragma unroll
  for (int d=0; d<24; ++d){ acc0[d] = wred_sum(acc0[d]); acc1[d] = wred_sum(acc1[d]); }
  if (lane == 0){
    float* op0 = out + (base + tq)*HID + hoff;
    float* op1 = op0 + HID;
#pragma unroll
    for (int d4=0; d4<6; ++d4){
      float4 t0 = {acc0[d4*4], acc0[d4*4+1], acc0[d4*4+2], acc0[d4*4+3]};
      float4 t1 = {acc1[d4*4], acc1[d4*4+1], acc1[d4*4+2], acc1[d4*4+3]};
      *(float4*)(op0 + d4*4) = t0;
      *(float4*)(op1 + d4*4) = t1;
    }
  }
}

// ---------------- dense attention for t = T-1 only (encoder 2)
__global__ __launch_bounds__(64)
void attn_last_kernel(const float* __restrict__ qkv, float* __restrict__ out)
{
  const int bh = blockIdx.x, b = bh>>2, h = bh&3;
  const int lane = threadIdx.x;
  const size_t base = (size_t)b*T_SEQ;
  const int hoff = h*HDIM;
  float q[24];
  {
    const float* qp = qkv + (base + T_SEQ-1)*QKV_LD + hoff;
#pragma unroll
    for (int d4=0; d4<6; ++d4){
      float4 t = *(const float4*)(qp + d4*4);
      q[d4*4]=t.x; q[d4*4+1]=t.y; q[d4*4+2]=t.z; q[d4*4+3]=t.w;
    }
  }
  float sc[16];
#pragma unroll 4
  for (int i=0;i<16;++i){
    const float* kp = qkv + (base + i*64 + lane)*QKV_LD + 96 + hoff;
    float a = 0.f;
#pragma unroll
    for (int d4=0; d4<6; ++d4){
      float4 kv = *(const float4*)(kp + d4*4);
      a += q[d4*4]*kv.x + q[d4*4+1]*kv.y + q[d4*4+2]*kv.z + q[d4*4+3]*kv.w;
    }
    sc[i] = a*SCALE;
  }
  float m_loc = sc[0];
#pragma unroll
  for (int i=1;i<16;++i) m_loc = fmaxf(m_loc, sc[i]);
  const float m = wred_max(m_loc);
  float sum_loc = 0.f;
#pragma unroll
  for (int i=0;i<16;++i){ sc[i] = __expf(sc[i]-m); sum_loc += sc[i]; }
  const float inv = 1.f / wred_sum(sum_loc);
  float acc[24] = {};
#pragma unroll 4
  for (int i=0;i<16;++i){
    const float* vp = qkv + (base + i*64 + lane)*QKV_LD + 192 + hoff;
    const float wgt = sc[i]*inv;
#pragma unroll
    for (int d4=0; d4<6; ++d4){
      float4 vv = *(const float4*)(vp + d4*4);
      acc[d4*4]   += wgt*vv.x; acc[d4*4+1] += wgt*vv.y;
      acc[d4*4+2] += wgt*vv.z; acc[d4*4+3] += wgt*vv.w;
    }
  }
#pragma unroll
  for (int d=0; d<24; ++d) acc[d] = wred_sum(acc[d]);
  if (lane == 0){
    float* op = out + (base + T_SEQ-1)*HID + hoff;
#pragma unroll
    for (int d4=0; d4<6; ++d4){
      float4 t = {acc[d4*4], acc[d4*4+1], acc[d4*4+2], acc[d4*4+3]};
      *(float4*)(op + d4*4) = t;
    }
  }
}

// ---------------- out = LayerNorm(x + y) * w + b ; one wave per 96-wide row
__global__ __launch_bounds__(256)
void resln_kernel(const float* __restrict__ x, const float* __restrict__ y,
                  const float* __restrict__ w, const float* __restrict__ bb,
                  float* __restrict__ out)
{
  const int row = blockIdx.x*4 + (threadIdx.x>>6);
  const int lane = threadIdx.x & 63;
  const float* xr = x + (size_t)row*HID;
  const float* yr = y + (size_t)row*HID;
  float v0 = xr[lane] + yr[lane];
  float v1 = (lane < 32) ? (xr[64+lane] + yr[64+lane]) : 0.f;
  float mu = wred_sum(v0+v1) * (1.f/96.f);
  float d0 = v0-mu, d1 = (lane<32) ? (v1-mu) : 0.f;
  float var = wred_sum(d0*d0 + d1*d1) * (1.f/96.f);
  float rs = rsqrtf(var + 1e-5f);
  float* orow = out + (size_t)row*HID;
  orow[lane] = d0*rs*w[lane] + bb[lane];
  if (lane < 32) orow[64+lane] = d1*rs*w[64+lane] + bb[64+lane];
}

// ---------------- encoder-2 tail at t=T-1 only: proj+LN1+FF+LN2+fc
__device__ __forceinline__ float block_sum_192(float v, float* red){
  v = wred_sum(v);
  const int tid = threadIdx.x;
  if ((tid & 63) == 0) red[tid>>6] = v;
  __syncthreads();
  float r = red[0]+red[1]+red[2];
  __syncthreads();
  return r;
}

__global__ __launch_bounds__(192)
void tail_kernel(const float* __restrict__ xin, const float* __restrict__ mha,
                 const float* __restrict__ out_w, const float* __restrict__ out_b,
                 const float* __restrict__ l1_w, const float* __restrict__ l1_b,
                 const float* __restrict__ l2_w, const float* __restrict__ l2_b,
                 const float* __restrict__ ln1w, const float* __restrict__ ln1b,
                 const float* __restrict__ ln2w, const float* __restrict__ ln2b,
                 const float* __restrict__ fcw, const float* __restrict__ fcb,
                 float* __restrict__ outp)
{
  const int b = blockIdx.x, tid = threadIdx.x;
  __shared__ float y[96], f1[192], mrow[96], red[3];
  const size_t row = ((size_t)b*T_SEQ + T_SEQ-1)*HID;
  if (tid < 96) mrow[tid] = mha[row + tid];
  __syncthreads();
  float r = 0.f;
  if (tid < 96){
    float p = out_b[tid];
    const float* wr = out_w + tid*96;
#pragma unroll 4
    for (int d=0; d<96; ++d) p += mrow[d]*wr[d];
    r = xin[row + tid] + p;
  }
  float mu = block_sum_192(tid<96 ? r : 0.f, red) * (1.f/96.f);
  float dv = tid<96 ? r-mu : 0.f;
  float var = block_sum_192(dv*dv, red) * (1.f/96.f);
  float rs = rsqrtf(var + 1e-5f);
  if (tid < 96) y[tid] = dv*rs*ln1w[tid] + ln1b[tid];
  __syncthreads();
  {
    float a = l1_b[tid];
    const float* wr = l1_w + tid*96;
#pragma unroll 4
    for (int d=0; d<96; ++d) a += y[d]*wr[d];
    f1[tid] = fmaxf(a, 0.f);
  }
  __syncthreads();
  float r2 = 0.f;
  if (tid < 96){
    float a = l2_b[tid];
    const float* wr = l2_w + tid*192;
#pragma unroll 4
    for (int d=0; d<192; ++d) a += f1[d]*wr[d];
    r2 = y[tid] + a;
  }
  float mu2 = block_sum_192(tid<96 ? r2 : 0.f, red) * (1.f/96.f);
  float dv2 = tid<96 ? r2-mu2 : 0.f;
  float var2 = block_sum_192(dv2*dv2, red) * (1.f/96.f);
  float rs2 = rsqrtf(var2 + 1e-5f);
  float z = tid<96 ? (dv2*rs2*ln2w[tid] + ln2b[tid]) : 0.f;
  float tot = block_sum_192(tid<96 ? z*fcw[tid] : 0.f, red);
  if (tid == 0) outp[b] = tot + fcb[0];
}

extern "C" void kernel_launch(void* const* d_in, const int* in_sizes, int n_in,
                              void* d_out, int out_size, void* d_ws, size_t ws_size,
                              hipStream_t stream)
{
  const float* x     = (const float*)d_in[0];
  const float* w_ih0 = (const float*)d_in[1];
  const float* w_hh0 = (const float*)d_in[2];
  const float* b_ih0 = (const float*)d_in[3];
  const float* b_hh0 = (const float*)d_in[4];
  const float* w_ih1 = (const float*)d_in[5];
  const float* w_hh1 = (const float*)d_in[6];
  const float* b_ih1 = (const float*)d_in[7];
  const float* b_hh1 = (const float*)d_in[8];
  const float* qw = (const float*)d_in[9];
  const float* kw = (const float*)d_in[10];
  const float* vw = (const float*)d_in[11];
  const float* ow = (const float*)d_in[12];
  const float* enc_in_w  = (const float*)d_in[13];
  const float* enc_in_b  = (const float*)d_in[14];
  const float* enc_out_w = (const float*)d_in[15];
  const float* enc_out_b = (const float*)d_in[16];
  const float* enc_l1_w  = (const float*)d_in[17];
  const float* enc_l1_b  = (const float*)d_in[18];
  const float* enc_l2_w  = (const float*)d_in[19];
  const float* enc_l2_b  = (const float*)d_in[20];
  const float* enc_ln1_w = (const float*)d_in[21];
  const float* enc_ln1_b = (const float*)d_in[22];
  const float* enc_ln2_w = (const float*)d_in[23];
  const float* enc_ln2_b = (const float*)d_in[24];
  const float* fc_w = (const float*)d_in[25];
  const float* fc_b = (const float*)d_in[26];
  float* outp = (float*)d_out;

  float* ws = (float*)d_ws;
  const size_t MT = (size_t)BATCH*T_SEQ;   // 16384
  float* pre  = ws;                        // 16384*384 (also qkv[288] / ff1[192])
  float* bufA = pre  + MT*G4;
  float* bufB = bufA + MT*HID;
  float* bufC = bufB + MT*HID;
  float* wqkv = bufC + MT*HID;             // 288*96 packed qkv weights

  auto gemm = [&](const float* A, const float* W, const float* bb1, const float* bb2,
                  float* C, int N, int K, int ldc, int coff, int relu){
    dim3 grid((N+63)/64, 128);
    if (K == 64)
      gemm_mfma<64><<<grid, dim3(256), 0, stream>>>(A, W, bb1, bb2, C, N, ldc, coff, relu);
    else if (K == 96)
      gemm_mfma<96><<<grid, dim3(256), 0, stream>>>(A, W, bb1, bb2, C, N, ldc, coff, relu);
    else
      gemm_mfma<192><<<grid, dim3(256), 0, stream>>>(A, W, bb1, bb2, C, N, ldc, coff, relu);
  };

  pack_qkv_kernel<<<dim3(108), dim3(256), 0, stream>>>(qw, kw, vw, wqkv);

  // LSTM layer 0
  gemm(x, w_ih0, b_ih0, b_hh0, pre, 384, 64, 384, 0, 0);
  lstm_kernel<<<dim3(BATCH), dim3(384), 0, stream>>>(pre, w_hh0, bufA);
  // LSTM layer 1
  gemm(bufA, w_ih1, b_ih1, b_hh1, pre, 384, 96, 384, 0, 0);
  lstm_kernel<<<dim3(BATCH), dim3(384), 0, stream>>>(pre, w_hh1, bufB);
  // sparse attention (fused qkv GEMM via packed weights)
  gemm(bufB, wqkv, nullptr, nullptr, pre, 288, 96, QKV_LD, 0, 0);
  attn_kernel<<<dim3(4096), dim3(512), 0, stream>>>(pre, bufA, 1);
  gemm(bufA, ow, nullptr, nullptr, bufB, 96, 96, 96, 0, 0);
  // encoder layer 0 (full)
  gemm(bufB, enc_in_w, enc_in_b, nullptr, pre, 288, 96, QKV_LD, 0, 0);
  attn_kernel<<<dim3(4096), dim3(512), 0, stream>>>(pre, bufA, 0);
  gemm(bufA, enc_out_w, enc_out_b, nullptr, bufC, 96, 96, 96, 0, 0);
  resln_kernel<<<dim3(4096), dim3(256), 0, stream>>>(bufB, bufC, enc_ln1_w, enc_ln1_b, bufB);
  gemm(bufB, enc_l1_w, enc_l1_b, nullptr, pre, 192, 96, 192, 0, 1);
  gemm(pre, enc_l2_w, enc_l2_b, nullptr, bufC, 96, 192, 96, 0, 0);
  resln_kernel<<<dim3(4096), dim3(256), 0, stream>>>(bufB, bufC, enc_ln2_w, enc_ln2_b, bufB);
  // encoder layer 1 — only t = T-1 reaches the output head
  gemm(bufB, enc_in_w + 288*96, enc_in_b + 288, nullptr, pre, 288, 96, QKV_LD, 0, 0);
  attn_last_kernel<<<dim3(64), dim3(64), 0, stream>>>(pre, bufA);
  tail_kernel<<<dim3(BATCH), dim3(192), 0, stream>>>(
      bufB, bufA,
      enc_out_w + 96*96, enc_out_b + 96,
      enc_l1_w + 192*96, enc_l1_b + 192,
      enc_l2_w + 96*192, enc_l2_b + 96,
      enc_ln1_w + 96, enc_ln1_b + 96,
      enc_ln2_w + 96, enc_ln2_b + 96,
      fc_w, fc_b, outp);
}